// Round 9
// baseline (80.091 us; speedup 1.0000x reference)
//
#include <hip/hip_runtime.h>
#include <math.h>

// NeRF ray-march forward (MipRayMarcher2), WAVE-AUTONOMOUS (zero barriers).
// Each 64-lane wave owns 16 rays (4 threads/ray) and a private LDS slice:
//   dep[48][17] + den[48][17] (transposed staging, coalesced global loads)
//   swei[47][17]              (staging for the dense coalesced weight store)
// Colors are loaded REGISTER-DIRECT (10 float4 per thread, 4-lane clusters
// cover cache lines) and fused into the march -> no v-pass, no color phase,
// no __syncthreads anywhere. Intra-wave LDS ordering: lockstep + in-order
// DS pipe (+ explicit lgkmcnt fences).
// nRays = 262144, 48 samples, 47 intervals.

#define S_SAMPLES 48
#define S_INTERVALS 47
#define WR 16            // rays per wave
#define PAD 17           // LDS row stride in dwords (odd -> spread banks)
#define WAVES 2          // waves per block
#define BT (WAVES * 64)

#define DEP_OFF 0
#define DEN_OFF (S_SAMPLES * PAD)                       // 816
#define WEI_OFF (2 * S_SAMPLES * PAD)                   // 1632
#define WAVE_LDS (2 * S_SAMPLES * PAD + S_INTERVALS * PAD)  // 2431 dwords

__global__ __launch_bounds__(BT) void raymarch_kernel(
    const float* __restrict__ colors,     // [nRays, 48, 3]
    const float* __restrict__ densities,  // [nRays, 48]
    const float* __restrict__ depths,     // [nRays, 48]
    float* __restrict__ bmin,             // [nWaves] per-wave depth min
    float* __restrict__ bmax,             // [nWaves] per-wave depth max
    float* __restrict__ out_rgb,          // [nRays, 3]
    float* __restrict__ out_depth,        // [nRays] (unclamped here)
    float* __restrict__ out_w,            // [nRays, 47]
    int nRays) {
    __shared__ float smem[WAVES * WAVE_LDS];
    const int wid = threadIdx.x >> 6;
    const int lane = threadIdx.x & 63;
    float* Wb = smem + wid * WAVE_LDS;

    const int waveId = blockIdx.x * WAVES + wid;
    const size_t wray = (size_t)waveId * WR;  // first ray of this wave

    // ===== dep/den: coalesced global -> transposed wave-private LDS =====
    {
        const float4* gdep = (const float4*)(depths + wray * S_SAMPLES);
        const float4* gden = (const float4*)(densities + wray * S_SAMPLES);
#pragma unroll
        for (int k = 0; k < 3; ++k) {
            int fidx = lane + k * 64;  // 0..191
            int g = fidx * 4;          // dword idx; s multiple of 4
            int ray = g / S_SAMPLES;
            int s = g - ray * S_SAMPLES;
            float4 vd = gdep[fidx];
            float4 vn = gden[fidx];
            Wb[DEP_OFF + (s + 0) * PAD + ray] = vd.x;
            Wb[DEP_OFF + (s + 1) * PAD + ray] = vd.y;
            Wb[DEP_OFF + (s + 2) * PAD + ray] = vd.z;
            Wb[DEP_OFF + (s + 3) * PAD + ray] = vd.w;
            Wb[DEN_OFF + (s + 0) * PAD + ray] = vn.x;
            Wb[DEN_OFF + (s + 1) * PAD + ray] = vn.y;
            Wb[DEN_OFF + (s + 2) * PAD + ray] = vn.z;
            Wb[DEN_OFF + (s + 3) * PAD + ray] = vn.w;
        }
    }

    const int r = lane >> 2;  // local ray 0..15
    const int q = lane & 3;   // quad slot: intervals 12q..12q+11

    // ===== colors: register-direct, 10 float4 of this thread's segment =====
    const float4* gcol = (const float4*)(colors + wray * (S_SAMPLES * 3));
    const int cb = r * 36 + 9 * q;  // f4 index of color dword 36q in ray r
    float4 c0 = gcol[cb + 0], c1 = gcol[cb + 1], c2 = gcol[cb + 2];
    float4 c3 = gcol[cb + 3], c4 = gcol[cb + 4], c5 = gcol[cb + 5];
    float4 c6 = gcol[cb + 6], c7 = gcol[cb + 7], c8 = gcol[cb + 8];
    float4 c9 = gcol[cb + ((q < 3) ? 9 : 8)];  // q==3: dummy (alpha=0 there)

    // wave-private LDS: writes above land before reads below (in-order DS
    // pipe within a wave); explicit fence as insurance.
    asm volatile("s_waitcnt lgkmcnt(0)" ::: "memory");

    // ===== march: 12 intervals, colors fused, weights in named regs =====
    const int sBase = 12 * q;
    const float LOG2E = 1.4426950408889634f;
    float dPrev = Wb[DEP_OFF + sBase * PAD + r];
    float nPrev = Wb[DEN_OFF + sBase * PAD + r];
    const float firstDep = dPrev;  // sample 0 for q==0

    float T = 1.f;
    float s0 = 0.f, s1 = 0.f, s2 = 0.f, aw = 0.f, ad = 0.f;
    float w0, w1, w2, w3, w4, w5, w6, w7, w8, w9, w10, w11;

#define MSTEP(J, W, HAS, CA0, CA1, CA2, CB0, CB1, CB2)                 \
    do {                                                               \
        const int row = (HAS) ? (sBase + (J) + 1) : (sBase + 11);      \
        float dN = Wb[DEP_OFF + row * PAD + r];                        \
        float nN = Wb[DEN_OFF + row * PAD + r];                        \
        float delta = dN - dPrev;                                      \
        float xs = (0.5f * (nPrev + nN) - 1.f) * LOG2E;                \
        float sp2 = fmaxf(xs, 0.f) + log2f(1.f + exp2f(-fabsf(xs)));   \
        float alpha = (HAS) ? (1.f - exp2f(-delta * sp2)) : 0.f;       \
        W = alpha * T;                                                 \
        T *= (1.f - alpha + 1e-10f);                                   \
        s0 = fmaf(W, 0.5f * ((CA0) + (CB0)), s0);                      \
        s1 = fmaf(W, 0.5f * ((CA1) + (CB1)), s1);                      \
        s2 = fmaf(W, 0.5f * ((CA2) + (CB2)), s2);                      \
        aw += W;                                                       \
        ad = fmaf(W, 0.5f * (dPrev + dN), ad);                         \
        dPrev = dN;                                                    \
        nPrev = nN;                                                    \
    } while (0)

    MSTEP(0, w0, true, c0.x, c0.y, c0.z, c0.w, c1.x, c1.y);
    MSTEP(1, w1, true, c0.w, c1.x, c1.y, c1.z, c1.w, c2.x);
    MSTEP(2, w2, true, c1.z, c1.w, c2.x, c2.y, c2.z, c2.w);
    MSTEP(3, w3, true, c2.y, c2.z, c2.w, c3.x, c3.y, c3.z);
    MSTEP(4, w4, true, c3.x, c3.y, c3.z, c3.w, c4.x, c4.y);
    MSTEP(5, w5, true, c3.w, c4.x, c4.y, c4.z, c4.w, c5.x);
    MSTEP(6, w6, true, c4.z, c4.w, c5.x, c5.y, c5.z, c5.w);
    MSTEP(7, w7, true, c5.y, c5.z, c5.w, c6.x, c6.y, c6.z);
    MSTEP(8, w8, true, c6.x, c6.y, c6.z, c6.w, c7.x, c7.y);
    MSTEP(9, w9, true, c6.w, c7.x, c7.y, c7.z, c7.w, c8.x);
    MSTEP(10, w10, true, c7.z, c7.w, c8.x, c8.y, c8.z, c8.w);
    MSTEP(11, w11, (q < 3), c8.y, c8.z, c8.w, c9.x, c9.y, c9.z);
#undef MSTEP

    // ===== exclusive product scan of local transmittance across the quad ==
    float P = T;
    float u1 = __shfl_up(P, 1);
    float pq = (q >= 1) ? P * u1 : P;
    float u2 = __shfl_up(pq, 2);
    float incl = (q >= 2) ? pq * u2 : pq;
    float u3 = __shfl_up(incl, 1);
    float Texc = (q >= 1) ? u3 : 1.f;

    // ===== Texc-scaled weights -> LDS (for the dense store) =====
    Wb[WEI_OFF + (sBase + 0) * PAD + r] = w0 * Texc;
    Wb[WEI_OFF + (sBase + 1) * PAD + r] = w1 * Texc;
    Wb[WEI_OFF + (sBase + 2) * PAD + r] = w2 * Texc;
    Wb[WEI_OFF + (sBase + 3) * PAD + r] = w3 * Texc;
    Wb[WEI_OFF + (sBase + 4) * PAD + r] = w4 * Texc;
    Wb[WEI_OFF + (sBase + 5) * PAD + r] = w5 * Texc;
    Wb[WEI_OFF + (sBase + 6) * PAD + r] = w6 * Texc;
    Wb[WEI_OFF + (sBase + 7) * PAD + r] = w7 * Texc;
    Wb[WEI_OFF + (sBase + 8) * PAD + r] = w8 * Texc;
    Wb[WEI_OFF + (sBase + 9) * PAD + r] = w9 * Texc;
    Wb[WEI_OFF + (sBase + 10) * PAD + r] = w10 * Texc;
    if (q < 3) Wb[WEI_OFF + (sBase + 11) * PAD + r] = w11 * Texc;

    // ===== quad reduction of the 5 sums =====
    s0 *= Texc; s1 *= Texc; s2 *= Texc; aw *= Texc; ad *= Texc;
#pragma unroll
    for (int off = 1; off <= 2; off <<= 1) {
        s0 += __shfl_xor(s0, off);
        s1 += __shfl_xor(s1, off);
        s2 += __shfl_xor(s2, off);
        aw += __shfl_xor(aw, off);
        ad += __shfl_xor(ad, off);
    }
    if (q == 0) {
        size_t ray = wray + r;
        size_t rb = ray * 3;
        out_rgb[rb + 0] = fmaf(s0, 2.f, -1.f);
        out_rgb[rb + 1] = fmaf(s1, 2.f, -1.f);
        out_rgb[rb + 2] = fmaf(s2, 2.f, -1.f);
        out_depth[ray] = ad / aw;  // NaN fixed in clamp pass
    }

    // ===== per-wave depth min/max (depths sorted along samples) =====
    float mnd = (q == 0) ? firstDep : INFINITY;  // sample 0
    float mxd = (q == 3) ? dPrev : -INFINITY;    // sample 47
#pragma unroll
    for (int off = 32; off; off >>= 1) {
        mnd = fminf(mnd, __shfl_xor(mnd, off));
        mxd = fmaxf(mxd, __shfl_xor(mxd, off));
    }
    if (lane == 0) {
        bmin[waveId] = mnd;
        bmax[waveId] = mxd;
    }

    // swei complete (in-order DS pipe); fence as insurance.
    asm volatile("s_waitcnt lgkmcnt(0)" ::: "memory");

    // ===== weight store: LDS -> dense coalesced global =====
    {
        float* gw = out_w + wray * S_INTERVALS;
#pragma unroll
        for (int k = 0; k < 12; ++k) {
            int g = lane + k * 64;
            if (g < WR * S_INTERVALS) {  // 752
                int ray = g / S_INTERVALS;
                int s = g - ray * S_INTERVALS;
                gw[g] = Wb[WEI_OFF + s * PAD + ray];
            }
        }
    }
}

// Fold 16384 per-wave minima/maxima into g[0]=gmin, g[1]=gmax. One block.
__global__ __launch_bounds__(1024) void reduce_minmax_kernel(
    const float* __restrict__ bmin, const float* __restrict__ bmax,
    float* __restrict__ g, int n) {
    float mn = INFINITY, mx = -INFINITY;
    for (int i = threadIdx.x; i < n; i += 1024) {
        mn = fminf(mn, bmin[i]);
        mx = fmaxf(mx, bmax[i]);
    }
#pragma unroll
    for (int off = 32; off; off >>= 1) {
        mn = fminf(mn, __shfl_xor(mn, off));
        mx = fmaxf(mx, __shfl_xor(mx, off));
    }
    __shared__ float smn[16], smx[16];
    const int wid = threadIdx.x >> 6;
    if ((threadIdx.x & 63) == 0) {
        smn[wid] = mn;
        smx[wid] = mx;
    }
    __syncthreads();
    if (threadIdx.x == 0) {
        float m = INFINITY, M = -INFINITY;
#pragma unroll
        for (int i = 0; i < 16; ++i) {
            m = fminf(m, smn[i]);
            M = fmaxf(M, smx[i]);
        }
        g[0] = m;
        g[1] = M;
    }
}

__global__ __launch_bounds__(256) void clamp_depth_kernel(
    float* __restrict__ out_depth, const float* __restrict__ g, int n) {
    int i = blockIdx.x * blockDim.x + threadIdx.x;
    if (i < n) {
        float gmin = g[0];
        float gmax = g[1];
        float d = out_depth[i];
        if (isnan(d)) d = INFINITY;  // nan_to_num(nan=inf)
        d = fminf(fmaxf(d, gmin), gmax);
        out_depth[i] = d;
    }
}

extern "C" void kernel_launch(void* const* d_in, const int* in_sizes, int n_in,
                              void* d_out, int out_size, void* d_ws, size_t ws_size,
                              hipStream_t stream) {
    const float* colors = (const float*)d_in[0];
    const float* densities = (const float*)d_in[1];
    const float* depths = (const float*)d_in[2];

    const int nRays = in_sizes[2] / S_SAMPLES;  // 262144
    const int nWaves = nRays / WR;              // 16384
    const int nBlocks = nWaves / WAVES;         // 8192

    float* out = (float*)d_out;
    float* out_rgb = out;                        // nRays*3
    float* out_depth = out + (size_t)nRays * 3;  // nRays
    float* out_w = out + (size_t)nRays * 4;      // nRays*47

    // ws layout (floats): [0..1]=gmin/gmax, [2..2+nW)=bmin, [2+nW..)=bmax
    float* wsf = (float*)d_ws;
    float* g = wsf;
    float* bmin = wsf + 2;
    float* bmax = wsf + 2 + nWaves;

    raymarch_kernel<<<nBlocks, BT, 0, stream>>>(
        colors, densities, depths, bmin, bmax, out_rgb, out_depth, out_w, nRays);
    reduce_minmax_kernel<<<1, 1024, 0, stream>>>(bmin, bmax, g, nWaves);
    clamp_depth_kernel<<<(nRays + 255) / 256, 256, 0, stream>>>(out_depth, g, nRays);
}

// Round 10
// 61.450 us; speedup vs baseline: 1.3034x; 1.3034x over previous
//
#include <hip/hip_runtime.h>
#include <math.h>

// NeRF ray-march forward (MipRayMarcher2), WAVE-AUTONOMOUS + LDS color tiles.
// Each 64-lane wave owns 16 rays (4 threads/ray), private LDS slice:
//   dep[48][17] + den[48][17] (transposed staging; den reused as color tile)
//   wei[47][17]               (Texc-scaled weights; feeds store + rgb accum)
// ZERO barriers: all cross-thread traffic is intra-wave (lockstep, in-order
// DS pipe, lgkmcnt fences). Colors stream per-wave through the dead den tile
// in 3 chunks, register-staged & double-buffered so HBM latency hides under
// march / accumulation compute. nRays = 262144, 48 samples, 47 intervals.

#define S_SAMPLES 48
#define S_INTERVALS 47
#define WR 16   // rays per wave
#define PAD 17  // LDS row stride in dwords
#define WAVES 2
#define BT (WAVES * 64)

#define DEP_OFF 0
#define DEN_OFF (S_SAMPLES * PAD)                           // 816
#define WEI_OFF (2 * S_SAMPLES * PAD)                       // 1632
#define WAVE_LDS (2 * S_SAMPLES * PAD + S_INTERVALS * PAD)  // 2431 dwords

__global__ __launch_bounds__(BT, 4) void raymarch_kernel(
    const float* __restrict__ colors,     // [nRays, 48, 3]
    const float* __restrict__ densities,  // [nRays, 48]
    const float* __restrict__ depths,     // [nRays, 48]
    float* __restrict__ bmin,             // [nWaves] per-wave depth min
    float* __restrict__ bmax,             // [nWaves] per-wave depth max
    float* __restrict__ out_rgb,          // [nRays, 3]
    float* __restrict__ out_depth,        // [nRays] (unclamped here)
    float* __restrict__ out_w,            // [nRays, 47]
    int nRays) {
    __shared__ float smem[WAVES * WAVE_LDS];
    const int wid = threadIdx.x >> 6;
    const int lane = threadIdx.x & 63;
    float* Wb = smem + wid * WAVE_LDS;

    const int waveId = blockIdx.x * WAVES + wid;
    const size_t wray = (size_t)waveId * WR;  // first ray of this wave

    // ===== dep/den: coalesced global -> transposed wave-private LDS =====
    {
        const float4* gdep = (const float4*)(depths + wray * S_SAMPLES);
        const float4* gden = (const float4*)(densities + wray * S_SAMPLES);
#pragma unroll
        for (int k = 0; k < 3; ++k) {
            int fidx = lane + k * 64;  // 0..191
            int g = fidx * 4;          // dword idx; s multiple of 4
            int ray = g / S_SAMPLES;
            int s = g - ray * S_SAMPLES;
            float4 vd = gdep[fidx];
            float4 vn = gden[fidx];
            Wb[DEP_OFF + (s + 0) * PAD + ray] = vd.x;
            Wb[DEP_OFF + (s + 1) * PAD + ray] = vd.y;
            Wb[DEP_OFF + (s + 2) * PAD + ray] = vd.z;
            Wb[DEP_OFF + (s + 3) * PAD + ray] = vd.w;
            Wb[DEN_OFF + (s + 0) * PAD + ray] = vn.x;
            Wb[DEN_OFF + (s + 1) * PAD + ray] = vn.y;
            Wb[DEN_OFF + (s + 2) * PAD + ray] = vn.z;
            Wb[DEN_OFF + (s + 3) * PAD + ray] = vn.w;
        }
    }

    const int r = lane >> 2;  // local ray 0..15
    const int q = lane & 3;   // quad slot: intervals 12q..12q+11

    // ===== color chunk 0: issue coalesced loads NOW (hide under march) =====
    const float4* gcol4 = (const float4*)(colors + wray * (S_SAMPLES * 3));
    const int f0 = lane, f1 = lane + 64, f2 = lane + 128;
    const int rr0 = f0 / 12, i40 = f0 - rr0 * 12;
    const int rr1 = f1 / 12, i41 = f1 - rr1 * 12;
    const int rr2 = f2 / 12, i42 = f2 - rr2 * 12;
    float4 t0 = gcol4[rr0 * 36 + i40];
    float4 t1 = gcol4[rr1 * 36 + i41];
    float4 t2 = gcol4[rr2 * 36 + i42];

    // dep/den writes complete before march reads (in-order DS pipe); fence
    // as insurance.
    asm volatile("s_waitcnt lgkmcnt(0)" ::: "memory");

    // ===== march: quad-per-ray, weights in named registers =====
    const int sBase = 12 * q;
    const float LOG2E = 1.4426950408889634f;
    float dPrev = Wb[DEP_OFF + sBase * PAD + r];
    float nPrev = Wb[DEN_OFF + sBase * PAD + r];
    const float firstDep = dPrev;  // sample 0 for q==0

    float T = 1.f, aw = 0.f, ad = 0.f;
    float w0, w1, w2, w3, w4, w5, w6, w7, w8, w9, w10, w11;

#define MSTEP(J, W, HAS)                                               \
    do {                                                               \
        const int row = (HAS) ? (sBase + (J) + 1) : (sBase + 11);      \
        float dN = Wb[DEP_OFF + row * PAD + r];                        \
        float nN = Wb[DEN_OFF + row * PAD + r];                        \
        float delta = dN - dPrev;                                      \
        float xs = (0.5f * (nPrev + nN) - 1.f) * LOG2E;                \
        float sp2 = fmaxf(xs, 0.f) + log2f(1.f + exp2f(-fabsf(xs)));   \
        float alpha = (HAS) ? (1.f - exp2f(-delta * sp2)) : 0.f;       \
        W = alpha * T;                                                 \
        T *= (1.f - alpha + 1e-10f);                                   \
        aw += W;                                                       \
        ad = fmaf(W, 0.5f * (dPrev + dN), ad);                         \
        dPrev = dN;                                                    \
        nPrev = nN;                                                    \
    } while (0)

    MSTEP(0, w0, true);
    MSTEP(1, w1, true);
    MSTEP(2, w2, true);
    MSTEP(3, w3, true);
    MSTEP(4, w4, true);
    MSTEP(5, w5, true);
    MSTEP(6, w6, true);
    MSTEP(7, w7, true);
    MSTEP(8, w8, true);
    MSTEP(9, w9, true);
    MSTEP(10, w10, true);
    MSTEP(11, w11, (q < 3));
#undef MSTEP

    // ===== exclusive product scan across the quad =====
    float P = T;
    float u1s = __shfl_up(P, 1);
    float pq = (q >= 1) ? P * u1s : P;
    float u2s = __shfl_up(pq, 2);
    float incl = (q >= 2) ? pq * u2s : pq;
    float u3s = __shfl_up(incl, 1);
    float Texc = (q >= 1) ? u3s : 1.f;

    // ===== Texc-scaled weights -> LDS =====
    Wb[WEI_OFF + (sBase + 0) * PAD + r] = w0 * Texc;
    Wb[WEI_OFF + (sBase + 1) * PAD + r] = w1 * Texc;
    Wb[WEI_OFF + (sBase + 2) * PAD + r] = w2 * Texc;
    Wb[WEI_OFF + (sBase + 3) * PAD + r] = w3 * Texc;
    Wb[WEI_OFF + (sBase + 4) * PAD + r] = w4 * Texc;
    Wb[WEI_OFF + (sBase + 5) * PAD + r] = w5 * Texc;
    Wb[WEI_OFF + (sBase + 6) * PAD + r] = w6 * Texc;
    Wb[WEI_OFF + (sBase + 7) * PAD + r] = w7 * Texc;
    Wb[WEI_OFF + (sBase + 8) * PAD + r] = w8 * Texc;
    Wb[WEI_OFF + (sBase + 9) * PAD + r] = w9 * Texc;
    Wb[WEI_OFF + (sBase + 10) * PAD + r] = w10 * Texc;
    if (q < 3) Wb[WEI_OFF + (sBase + 11) * PAD + r] = w11 * Texc;

    // ===== quad reduction of depth/weight sums =====
    aw *= Texc;
    ad *= Texc;
#pragma unroll
    for (int off = 1; off <= 2; off <<= 1) {
        aw += __shfl_xor(aw, off);
        ad += __shfl_xor(ad, off);
    }
    if (q == 0) out_depth[wray + r] = ad / aw;  // NaN fixed in clamp pass

    // ===== per-wave depth min/max =====
    float mnd = (q == 0) ? firstDep : INFINITY;  // sample 0
    float mxd = (q == 3) ? dPrev : -INFINITY;    // sample 47
#pragma unroll
    for (int off = 32; off; off >>= 1) {
        mnd = fminf(mnd, __shfl_xor(mnd, off));
        mxd = fmaxf(mxd, __shfl_xor(mxd, off));
    }
    if (lane == 0) {
        bmin[waveId] = mnd;
        bmax[waveId] = mxd;
    }

    // wei writes complete (in-order DS pipe); fence as insurance.
    asm volatile("s_waitcnt lgkmcnt(0)" ::: "memory");

    // ===== weight store early: fire-and-forget, overlaps color phase =====
    {
        float* gw = out_w + wray * S_INTERVALS;
#pragma unroll
        for (int k = 0; k < 12; ++k) {
            int g = lane + k * 64;
            if (g < WR * S_INTERVALS) {  // 752
                int ray = g / S_INTERVALS;
                int s = g - ray * S_INTERVALS;
                gw[g] = Wb[WEI_OFF + s * PAD + ray];
            }
        }
    }

    // ===== color phase: 3 chunks through den tile, reg double-buffered =====
    float a0 = 0.f, a1 = 0.f, a2 = 0.f;
#pragma unroll
    for (int c = 0; c < 3; ++c) {
        // stage current chunk regs -> tile (WAR vs prev chunk's reads is
        // safe: in-order DS pipe per wave)
        Wb[DEN_OFF + (i40 * 4 + 0) * PAD + rr0] = t0.x;
        Wb[DEN_OFF + (i40 * 4 + 1) * PAD + rr0] = t0.y;
        Wb[DEN_OFF + (i40 * 4 + 2) * PAD + rr0] = t0.z;
        Wb[DEN_OFF + (i40 * 4 + 3) * PAD + rr0] = t0.w;
        Wb[DEN_OFF + (i41 * 4 + 0) * PAD + rr1] = t1.x;
        Wb[DEN_OFF + (i41 * 4 + 1) * PAD + rr1] = t1.y;
        Wb[DEN_OFF + (i41 * 4 + 2) * PAD + rr1] = t1.z;
        Wb[DEN_OFF + (i41 * 4 + 3) * PAD + rr1] = t1.w;
        Wb[DEN_OFF + (i42 * 4 + 0) * PAD + rr2] = t2.x;
        Wb[DEN_OFF + (i42 * 4 + 1) * PAD + rr2] = t2.y;
        Wb[DEN_OFF + (i42 * 4 + 2) * PAD + rr2] = t2.z;
        Wb[DEN_OFF + (i42 * 4 + 3) * PAD + rr2] = t2.w;
        if (c < 2) {  // issue next chunk's loads (hide under accumulation)
            float4 n0 = gcol4[rr0 * 36 + (c + 1) * 12 + i40];
            float4 n1 = gcol4[rr1 * 36 + (c + 1) * 12 + i41];
            float4 n2 = gcol4[rr2 * 36 + (c + 1) * 12 + i42];
            asm volatile("s_waitcnt lgkmcnt(0)" ::: "memory");
#pragma unroll
            for (int i = 0; i < 4; ++i) {
                int sl = 4 * q + i;
                int s = c * 16 + sl;
                float wlo = (s >= 1) ? Wb[WEI_OFF + (s - 1) * PAD + r] : 0.f;
                float whi = (s <= 46) ? Wb[WEI_OFF + s * PAD + r] : 0.f;
                float v = 0.5f * (wlo + whi);
                a0 = fmaf(v, Wb[DEN_OFF + (3 * sl + 0) * PAD + r], a0);
                a1 = fmaf(v, Wb[DEN_OFF + (3 * sl + 1) * PAD + r], a1);
                a2 = fmaf(v, Wb[DEN_OFF + (3 * sl + 2) * PAD + r], a2);
            }
            t0 = n0;
            t1 = n1;
            t2 = n2;
        } else {
            asm volatile("s_waitcnt lgkmcnt(0)" ::: "memory");
#pragma unroll
            for (int i = 0; i < 4; ++i) {
                int sl = 4 * q + i;
                int s = c * 16 + sl;
                float wlo = (s >= 1) ? Wb[WEI_OFF + (s - 1) * PAD + r] : 0.f;
                float whi = (s <= 46) ? Wb[WEI_OFF + s * PAD + r] : 0.f;
                float v = 0.5f * (wlo + whi);
                a0 = fmaf(v, Wb[DEN_OFF + (3 * sl + 0) * PAD + r], a0);
                a1 = fmaf(v, Wb[DEN_OFF + (3 * sl + 1) * PAD + r], a1);
                a2 = fmaf(v, Wb[DEN_OFF + (3 * sl + 2) * PAD + r], a2);
            }
        }
    }

    // ===== quad reduction of rgb sums =====
#pragma unroll
    for (int off = 1; off <= 2; off <<= 1) {
        a0 += __shfl_xor(a0, off);
        a1 += __shfl_xor(a1, off);
        a2 += __shfl_xor(a2, off);
    }
    if (q == 0) {
        size_t rb = (wray + r) * 3;
        out_rgb[rb + 0] = fmaf(a0, 2.f, -1.f);
        out_rgb[rb + 1] = fmaf(a1, 2.f, -1.f);
        out_rgb[rb + 2] = fmaf(a2, 2.f, -1.f);
    }
}

// Fold 16384 per-wave minima/maxima into g[0]=gmin, g[1]=gmax. One block.
__global__ __launch_bounds__(1024) void reduce_minmax_kernel(
    const float* __restrict__ bmin, const float* __restrict__ bmax,
    float* __restrict__ g, int n) {
    float mn = INFINITY, mx = -INFINITY;
    for (int i = threadIdx.x; i < n; i += 1024) {
        mn = fminf(mn, bmin[i]);
        mx = fmaxf(mx, bmax[i]);
    }
#pragma unroll
    for (int off = 32; off; off >>= 1) {
        mn = fminf(mn, __shfl_xor(mn, off));
        mx = fmaxf(mx, __shfl_xor(mx, off));
    }
    __shared__ float smn[16], smx[16];
    const int wid = threadIdx.x >> 6;
    if ((threadIdx.x & 63) == 0) {
        smn[wid] = mn;
        smx[wid] = mx;
    }
    __syncthreads();
    if (threadIdx.x == 0) {
        float m = INFINITY, M = -INFINITY;
#pragma unroll
        for (int i = 0; i < 16; ++i) {
            m = fminf(m, smn[i]);
            M = fmaxf(M, smx[i]);
        }
        g[0] = m;
        g[1] = M;
    }
}

__global__ __launch_bounds__(256) void clamp_depth_kernel(
    float* __restrict__ out_depth, const float* __restrict__ g, int n) {
    int i = blockIdx.x * blockDim.x + threadIdx.x;
    if (i < n) {
        float gmin = g[0];
        float gmax = g[1];
        float d = out_depth[i];
        if (isnan(d)) d = INFINITY;  // nan_to_num(nan=inf)
        d = fminf(fmaxf(d, gmin), gmax);
        out_depth[i] = d;
    }
}

extern "C" void kernel_launch(void* const* d_in, const int* in_sizes, int n_in,
                              void* d_out, int out_size, void* d_ws, size_t ws_size,
                              hipStream_t stream) {
    const float* colors = (const float*)d_in[0];
    const float* densities = (const float*)d_in[1];
    const float* depths = (const float*)d_in[2];

    const int nRays = in_sizes[2] / S_SAMPLES;  // 262144
    const int nWaves = nRays / WR;              // 16384
    const int nBlocks = nWaves / WAVES;         // 8192

    float* out = (float*)d_out;
    float* out_rgb = out;                        // nRays*3
    float* out_depth = out + (size_t)nRays * 3;  // nRays
    float* out_w = out + (size_t)nRays * 4;      // nRays*47

    // ws layout (floats): [0..1]=gmin/gmax, [2..2+nW)=bmin, [2+nW..)=bmax
    float* wsf = (float*)d_ws;
    float* g = wsf;
    float* bmin = wsf + 2;
    float* bmax = wsf + 2 + nWaves;

    raymarch_kernel<<<nBlocks, BT, 0, stream>>>(
        colors, densities, depths, bmin, bmax, out_rgb, out_depth, out_w, nRays);
    reduce_minmax_kernel<<<1, 1024, 0, stream>>>(bmin, bmax, g, nWaves);
    clamp_depth_kernel<<<(nRays + 255) / 256, 256, 0, stream>>>(out_depth, g, nRays);
}